// Round 5
// baseline (270.879 us; speedup 1.0000x reference)
//
#include <hip/hip_runtime.h>
#include <hip/hip_bf16.h>
#include <math.h>

#define B_N 8192
#define D_DIM 1024
#define NWORDS 128   // u64 words per mask row
#define NTILES 2080  // 64 diag + 2016 upper-triangle off-diag

using bf16 = __hip_bfloat16;
typedef float f32x4 __attribute__((ext_vector_type(4)));
typedef __bf16 bf16x8 __attribute__((ext_vector_type(8)));

// ws layout:
//   [0, 16MB)                : Xn bf16 [8192][1024]
//   [16MB, 24MB)             : maskbits u64 [8192][128]
//   red = 24MB:
//     red + 0      .. 32KB   : S[8192]  f32  (sum exp(sim-10), j != i)  [atomic, zeroed]
//     red + 32KB   .. 64KB   : P[8192]  f32  (popcount of mask row)     [written by pack]
//     red + 64KB   + 4       : flag u32  (mask-dtype detection)         [atomic, zeroed]
//     red + 64KB+256 ..      : Mpart[2080] f32 (per-block sum mask*sim) [written by sim]

__global__ void detect_mask_kernel(const unsigned* __restrict__ m, unsigned* __restrict__ flag) {
    unsigned c = 0;
    for (int i = blockIdx.x * blockDim.x + threadIdx.x; i < 262144;
         i += gridDim.x * blockDim.x) {
        c += (m[i] > 1u) ? 1u : 0u;
    }
    for (int s = 1; s < 64; s <<= 1) c += __shfl_xor(c, s, 64);
    if ((threadIdx.x & 63) == 0 && c) atomicAdd(flag, c);
}

// One thread per 64-bit output word (64 mask elements). Grid 4096 x 256.
__global__ void pack_mask_kernel(const unsigned char* __restrict__ m8,
                                 const int* __restrict__ m32,
                                 const unsigned* __restrict__ flag,
                                 unsigned long long* __restrict__ bits,
                                 float* __restrict__ P) {
    const bool is_u8 = (*flag != 0u);
    int tid = threadIdx.x;
    size_t w = (size_t)blockIdx.x * 256 + tid;
    unsigned long long word = 0;
    if (is_u8) {
        const uint4* src = (const uint4*)(m8 + w * 64);
#pragma unroll
        for (int q = 0; q < 4; ++q) {
            uint4 v = src[q];
            unsigned cs[4] = {v.x, v.y, v.z, v.w};
#pragma unroll
            for (int c = 0; c < 4; ++c) {
                unsigned u = ((cs[c] & 0x7F7F7F7Fu) + 0x7F7F7F7Fu) | cs[c];
                u &= 0x80808080u;
                unsigned nib = ((u >> 7) & 1u) | ((u >> 14) & 2u) | ((u >> 21) & 4u) | ((u >> 28) & 8u);
                word |= (unsigned long long)nib << ((q * 4 + c) * 4);
            }
        }
    } else {
        const uint4* src = (const uint4*)(m32 + w * 64);
#pragma unroll
        for (int q = 0; q < 16; ++q) {
            uint4 v = src[q];
            unsigned nib = (unsigned)(v.x != 0) | ((unsigned)(v.y != 0) << 1) |
                           ((unsigned)(v.z != 0) << 2) | ((unsigned)(v.w != 0) << 3);
            word |= (unsigned long long)nib << (q * 4);
        }
    }
    bits[w] = word;
    float pc = (float)__popcll(word);
    for (int s = 1; s < 64; s <<= 1) pc += __shfl_xor(pc, s, 64);
    __shared__ float wsum[4];
    if ((tid & 63) == 0) wsum[tid >> 6] = pc;
    __syncthreads();
    if (tid == 0)   P[blockIdx.x * 2]     = wsum[0] + wsum[1];
    if (tid == 128) P[blockIdx.x * 2 + 1] = wsum[2] + wsum[3];
}

__global__ void normalize_kernel(const float* __restrict__ emb, bf16* __restrict__ xn) {
    int row = blockIdx.x;
    int t = threadIdx.x;  // 256 threads, 4 floats each
    const float4* src = (const float4*)(emb + (size_t)row * D_DIM);
    float4 v = src[t];
    float ss = v.x * v.x + v.y * v.y + v.z * v.z + v.w * v.w;
    for (int s = 1; s < 64; s <<= 1) ss += __shfl_xor(ss, s, 64);
    __shared__ float wss[4];
    if ((t & 63) == 0) wss[t >> 6] = ss;
    __syncthreads();
    float tot = wss[0] + wss[1] + wss[2] + wss[3];
    float scale = 1.0f / fmaxf(sqrtf(tot), 1e-12f);
    ushort4 o;
    o.x = __builtin_bit_cast(unsigned short, __float2bfloat16(v.x * scale));
    o.y = __builtin_bit_cast(unsigned short, __float2bfloat16(v.y * scale));
    o.z = __builtin_bit_cast(unsigned short, __float2bfloat16(v.z * scale));
    o.w = __builtin_bit_cast(unsigned short, __float2bfloat16(v.w * scale));
    *reinterpret_cast<ushort4*>(xn + (size_t)row * D_DIM + t * 4) = o;
}

// Upper-triangle tiling: 64 diag + 2016 off-diag = 2080 blocks.
// 128x128 tile, BK=64, 4 waves (2x2), each wave 64x64 = 4x4 frags of 16x16x32.
// K-loop: 2-phase double-buffered LDS, ONE barrier per K-step; stage for
// kt+1 issued BEFORE compute of kt so the barrier's implicit vmcnt(0) lands
// after ~32 MFMAs of cover (T3-minimum recipe).
__global__ __launch_bounds__(256, 2) void sim_kernel(
    const bf16* __restrict__ xn,
    const unsigned long long* __restrict__ mbits,
    float* __restrict__ S, float* __restrict__ Mpart)
{
    __shared__ bf16 Abuf[2][128 * 64];
    __shared__ bf16 Bbuf[2][128 * 64];
    __shared__ float Mred[4];

    // XCD-aware bijective swizzle (2080 % 8 == 0 -> 260 per XCD)
    int b0 = blockIdx.x;
    int tile = (b0 & 7) * 260 + (b0 >> 3);
    int by, bx;
    bool isdiag;
    if (tile < 64) {
        by = bx = tile;
        isdiag = true;
    } else {
        int j = tile - 64;  // [0, 2016)
        int p = (int)((sqrt((double)(8 * j + 1)) + 1.0) * 0.5);
        while (p * (p - 1) / 2 > j) --p;
        while ((p + 1) * p / 2 <= j) ++p;
        int q = j - p * (p - 1) / 2;
        by = q; bx = p;  // by < bx
        isdiag = false;
    }

    int t = threadIdx.x;
    int w = t >> 6, lane = t & 63;
    int wm = w >> 1, wn = w & 1;
    int l15 = lane & 15, lg = lane >> 4;

    f32x4 acc[4][4];
#pragma unroll
    for (int i = 0; i < 4; i++)
#pragma unroll
        for (int j = 0; j < 4; j++) acc[i][j] = {0.f, 0.f, 0.f, 0.f};

    int arow0 = by << 7;
    int brow0 = bx << 7;

    // staging: 128x64 bf16 per matrix per K-step, 16B/lane async
    int ebase0 = w * 64;                 // wave-uniform part
    int e0 = ebase0 + lane;
    int r0 = e0 >> 3, c80 = (e0 & 7) << 3;

#define STAGE(bufidx, kt)                                                                   \
    {                                                                                       \
        _Pragma("unroll") for (int i = 0; i < 4; ++i) {                                     \
            int ebase = i * 256 + ebase0;                                                   \
            int r = (i * 256 + e0) >> 3;                                                    \
            const bf16* gA = xn + (size_t)(arow0 + r) * D_DIM + (kt) * 64 + c80;            \
            const bf16* gB = xn + (size_t)(brow0 + r) * D_DIM + (kt) * 64 + c80;            \
            char* lA = (char*)(&Abuf[bufidx][0]) + (size_t)ebase * 16;                      \
            char* lB = (char*)(&Bbuf[bufidx][0]) + (size_t)ebase * 16;                      \
            __builtin_amdgcn_global_load_lds((const __attribute__((address_space(1))) void*)gA, \
                                             (__attribute__((address_space(3))) void*)lA, 16, 0, 0); \
            __builtin_amdgcn_global_load_lds((const __attribute__((address_space(1))) void*)gB, \
                                             (__attribute__((address_space(3))) void*)lB, 16, 0, 0); \
        }                                                                                   \
    }

    STAGE(0, 0);
    __syncthreads();  // vmcnt(0) drain: buf0 ready

    for (int kt = 0; kt < 16; ++kt) {
        int cur = kt & 1;
        if (kt < 15) STAGE(cur ^ 1, kt + 1);  // issue next tile's loads FIRST
#pragma unroll
        for (int kk = 0; kk < 2; ++kk) {
            bf16x8 a[4], b[4];
#pragma unroll
            for (int f = 0; f < 4; ++f) {
                a[f] = *reinterpret_cast<const bf16x8*>(&Abuf[cur][0] + (wm * 64 + f * 16 + l15) * 64 + kk * 32 + lg * 8);
                b[f] = *reinterpret_cast<const bf16x8*>(&Bbuf[cur][0] + (wn * 64 + f * 16 + l15) * 64 + kk * 32 + lg * 8);
            }
#pragma unroll
            for (int fm = 0; fm < 4; ++fm)
#pragma unroll
                for (int fn = 0; fn < 4; ++fn)
                    acc[fm][fn] = __builtin_amdgcn_mfma_f32_16x16x32_bf16(a[fm], b[fn], acc[fm][fn], 0, 0, 0);
        }
        if (kt < 15) __syncthreads();  // single barrier/K-step: drains stage loads
    }
#undef STAGE

    // ---- Epilogue ----
    // C/D layout: col = l15, row = lg*4 + reg (within 16x16 frag).
    float colE[4] = {0.f, 0.f, 0.f, 0.f};
    unsigned long long wcol[4] = {0, 0, 0, 0};
    if (!isdiag) {
#pragma unroll
        for (int fn = 0; fn < 4; ++fn) {
            int gc = brow0 + wn * 64 + fn * 16 + l15;
            wcol[fn] = mbits[(size_t)gc * NWORDS + by * 2 + wm];
        }
    }

    float Mloc = 0.f;
#pragma unroll
    for (int fm = 0; fm < 4; ++fm) {
#pragma unroll
        for (int reg = 0; reg < 4; ++reg) {
            int lr = fm * 16 + lg * 4 + reg;          // row within wave tile
            int gr = arow0 + wm * 64 + lr;
            unsigned long long wrow = mbits[(size_t)gr * NWORDS + bx * 2 + wn];
            float E = 0.f;
#pragma unroll
            for (int fn = 0; fn < 4; ++fn) {
                int gc = brow0 + wn * 64 + fn * 16 + l15;
                float sim = acc[fm][fn][reg] * 10.0f;
                float e = __expf(sim - 10.0f);
                if (isdiag && gr == gc) e = 0.f;
                E += e;
                if ((wrow >> (fn * 16 + l15)) & 1ull) Mloc += sim;
                if (!isdiag) {
                    colE[fn] += e;
                    if ((wcol[fn] >> lr) & 1ull) Mloc += sim;
                }
            }
            E += __shfl_xor(E, 1, 64);
            E += __shfl_xor(E, 2, 64);
            E += __shfl_xor(E, 4, 64);
            E += __shfl_xor(E, 8, 64);
            if (l15 == 0) atomicAdd(&S[gr], E);
        }
    }

    if (!isdiag) {
#pragma unroll
        for (int fn = 0; fn < 4; ++fn) {
            float E = colE[fn];
            E += __shfl_xor(E, 16, 64);
            E += __shfl_xor(E, 32, 64);
            if (lg == 0) atomicAdd(&S[brow0 + wn * 64 + fn * 16 + l15], E);
        }
    }

    for (int s = 1; s < 64; s <<= 1) Mloc += __shfl_xor(Mloc, s, 64);
    __syncthreads();  // waves may still be in MFMA loop; sync before Mred reuse
    if (lane == 0) Mred[w] = Mloc;
    __syncthreads();
    if (t == 0) Mpart[b0] = Mred[0] + Mred[1] + Mred[2] + Mred[3];
}

__global__ void finalize_kernel(const float* __restrict__ S, const float* __restrict__ P,
                                const float* __restrict__ Mpart, float* __restrict__ out) {
    int t = threadIdx.x;  // 1024
    double a = 0.0;
    for (int i = t; i < B_N; i += 1024) {
        float lse = 10.0f + logf(S[i]);
        a += (double)P[i] * (double)lse;
    }
    for (int i = t; i < NTILES; i += 1024) a -= (double)Mpart[i];
    for (int s = 1; s < 64; s <<= 1) a += __shfl_xor(a, s, 64);
    __shared__ double sh[16];
    if ((t & 63) == 0) sh[t >> 6] = a;
    __syncthreads();
    if (t == 0) {
        double tot = 0.0;
        for (int i = 0; i < 16; ++i) tot += sh[i];
        out[0] = (float)(tot / (double)B_N);
    }
}

extern "C" void kernel_launch(void* const* d_in, const int* in_sizes, int n_in,
                              void* d_out, int out_size, void* d_ws, size_t ws_size,
                              hipStream_t stream) {
    const float* emb = (const float*)d_in[0];
    const void* mask = d_in[1];
    char* ws = (char*)d_ws;
    bf16* xn = (bf16*)ws;
    const size_t XN_BYTES = (size_t)B_N * D_DIM * 2;              // 16MB
    unsigned long long* mbits = (unsigned long long*)(ws + XN_BYTES);
    const size_t MB_BYTES = (size_t)B_N * NWORDS * 8;             // 8MB
    char* red = ws + XN_BYTES + MB_BYTES;
    float* S = (float*)red;
    float* P = (float*)(red + 32768);
    unsigned* flag = (unsigned*)(red + 65536 + 4);
    float* Mpart = (float*)(red + 65536 + 256);

    hipMemsetAsync(red, 0, 65536 + 16, stream);
    detect_mask_kernel<<<64, 256, 0, stream>>>((const unsigned*)mask, flag);
    pack_mask_kernel<<<4096, 256, 0, stream>>>((const unsigned char*)mask, (const int*)mask,
                                               flag, mbits, P);
    normalize_kernel<<<B_N, 256, 0, stream>>>(emb, xn);
    sim_kernel<<<NTILES, 256, 0, stream>>>(xn, mbits, S, Mpart);
    finalize_kernel<<<1, 1024, 0, stream>>>(S, P, Mpart, (float*)d_out);
}

// Round 6
// 247.650 us; speedup vs baseline: 1.0938x; 1.0938x over previous
//
#include <hip/hip_runtime.h>
#include <hip/hip_bf16.h>
#include <math.h>

#define B_N 8192
#define D_DIM 1024
#define NTILES 2080  // 64 diag + 2016 upper-triangle off-diag

using bf16 = __hip_bfloat16;
typedef float f32x4 __attribute__((ext_vector_type(4)));
typedef __bf16 bf16x8 __attribute__((ext_vector_type(8)));

// ws layout:
//   [0, 16MB)              : Xn bf16 [8192][1024]
//   red = 16MB:
//     red + 0      .. 32KB : S[8192]  f32 (sum exp(sim-10), j != i) [atomic, zeroed]
//     red + 32KB   .. 64KB : P[8192]  f32 (mask row count)          [atomic, zeroed]
//     red + 64KB   + 4     : flag u32 (mask-dtype detection)        [atomic, zeroed]
//     red + 64KB+256 ..    : Mpart[2080] f32 (per-block sum mask*sim)

__global__ void detect_mask_kernel(const unsigned* __restrict__ m, unsigned* __restrict__ flag) {
    // Read first 1MB as u32. u8-bool mask at ~1% density -> ~3% of words >1.
    // i32 mask -> all words in {0,1} -> flag stays 0.
    unsigned c = 0;
    for (int i = blockIdx.x * blockDim.x + threadIdx.x; i < 262144;
         i += gridDim.x * blockDim.x) {
        c += (m[i] > 1u) ? 1u : 0u;
    }
    for (int s = 1; s < 64; s <<= 1) c += __shfl_xor(c, s, 64);
    if ((threadIdx.x & 63) == 0 && c) atomicAdd(flag, c);
}

__global__ void normalize_kernel(const float* __restrict__ emb, bf16* __restrict__ xn) {
    int row = blockIdx.x;
    int t = threadIdx.x;  // 256 threads, 4 floats each
    const float4* src = (const float4*)(emb + (size_t)row * D_DIM);
    float4 v = src[t];
    float ss = v.x * v.x + v.y * v.y + v.z * v.z + v.w * v.w;
    for (int s = 1; s < 64; s <<= 1) ss += __shfl_xor(ss, s, 64);
    __shared__ float wss[4];
    if ((t & 63) == 0) wss[t >> 6] = ss;
    __syncthreads();
    float tot = wss[0] + wss[1] + wss[2] + wss[3];
    float scale = 1.0f / fmaxf(sqrtf(tot), 1e-12f);
    ushort4 o;
    o.x = __builtin_bit_cast(unsigned short, __float2bfloat16(v.x * scale));
    o.y = __builtin_bit_cast(unsigned short, __float2bfloat16(v.y * scale));
    o.z = __builtin_bit_cast(unsigned short, __float2bfloat16(v.z * scale));
    o.w = __builtin_bit_cast(unsigned short, __float2bfloat16(v.w * scale));
    *reinterpret_cast<ushort4*>(xn + (size_t)row * D_DIM + t * 4) = o;
}

// Upper-triangle tiling: 64 diag + 2016 off-diag = 2080 blocks.
// 128x128 tile, BK=64, 4 waves (2x2), each wave 64x64 = 4x4 frags of 16x16x32.
// K-loop = R4's proven single-buffer shape (R5's explicit dbuf regressed:
// 64KB LDS cut co-resident blocks that were doing the latency hiding).
// NEW: the mask is streamed INSIDE the K-loop (8 dword loads per K-step,
// issued after the MFMA cluster -> a full K-step of cover, drained by the
// next barrier) and packed into 2 per-thread u64s for the epilogue. This
// deletes the serial 256MB pack_mask_kernel (~42us).
__global__ __launch_bounds__(256, 2) void sim_kernel(
    const bf16* __restrict__ xn,
    const unsigned char* __restrict__ m8,
    const int* __restrict__ m32,
    const unsigned* __restrict__ flag,
    float* __restrict__ S, float* __restrict__ Pp, float* __restrict__ Mpart)
{
    __shared__ bf16 Abuf[128 * 64];
    __shared__ bf16 Bbuf[128 * 64];
    __shared__ float Mred[4];

    // XCD-aware bijective swizzle (2080 % 8 == 0 -> 260 per XCD)
    int b0 = blockIdx.x;
    int tile = (b0 & 7) * 260 + (b0 >> 3);
    int by, bx;
    bool isdiag;
    if (tile < 64) {
        by = bx = tile;
        isdiag = true;
    } else {
        int j = tile - 64;  // [0, 2016)
        int p = (int)((sqrt((double)(8 * j + 1)) + 1.0) * 0.5);
        while (p * (p - 1) / 2 > j) --p;
        while ((p + 1) * p / 2 <= j) ++p;
        int q = j - p * (p - 1) / 2;
        by = q; bx = p;  // by < bx
        isdiag = false;
    }

    int t = threadIdx.x;
    int w = t >> 6, lane = t & 63;
    int wm = w >> 1, wn = w & 1;
    int l15 = lane & 15, lg = lane >> 4;

    const bool is_u8 = (*flag != 0u);

    f32x4 acc[4][4];
#pragma unroll
    for (int i = 0; i < 4; i++)
#pragma unroll
        for (int j = 0; j < 4; j++) acc[i][j] = {0.f, 0.f, 0.f, 0.f};

    int arow0 = by << 7;
    int brow0 = bx << 7;

    int ebase0 = w * 64;
    int e0 = ebase0 + lane;
    int c80 = (e0 & 7) << 3;

    // mask prefetch state: 8 values in flight, 2 packed u64 accumulators
    unsigned long long row_bits = 0ull, col_bits = 0ull;
    int vb[8];  // statically indexed under full unroll only

    // kt 0..7  -> row-side batches: (fm,rg) pairs idx = kt*2+{0,1}, 4 fn each
    //             bit position fm*16 + rg*4 + fn
    // kt 8..15 -> col-side batches (off-diag only): idx = (kt-8)*2+{0,1}
    //             bit position fn*16 + fm*4 + rg
#pragma unroll
    for (int kt = 0; kt < 16; ++kt) {
        // stage A,B tiles (128x64 bf16 = 16KB each), linear LDS, width-16 async
#pragma unroll
        for (int i = 0; i < 4; ++i) {
            int ebase = i * 256 + ebase0;
            int r = (i * 256 + e0) >> 3;
            const bf16* gA = xn + (size_t)(arow0 + r) * D_DIM + kt * 64 + c80;
            const bf16* gB = xn + (size_t)(brow0 + r) * D_DIM + kt * 64 + c80;
            char* lA = (char*)Abuf + (size_t)ebase * 16;
            char* lB = (char*)Bbuf + (size_t)ebase * 16;
            __builtin_amdgcn_global_load_lds((const __attribute__((address_space(1))) void*)gA,
                                             (__attribute__((address_space(3))) void*)lA, 16, 0, 0);
            __builtin_amdgcn_global_load_lds((const __attribute__((address_space(1))) void*)gB,
                                             (__attribute__((address_space(3))) void*)lB, 16, 0, 0);
        }
        __syncthreads();  // drains staging AND previous kt's mask loads

        // pack previous kt's mask batch (pure VALU; values guaranteed landed)
        if (kt > 0 && kt <= 8) {
#pragma unroll
            for (int j = 0; j < 2; ++j) {
                int idx = (kt - 1) * 2 + j;
                int fm = idx >> 2, rg = idx & 3;
#pragma unroll
                for (int fn = 0; fn < 4; ++fn)
                    row_bits |= (unsigned long long)(vb[j * 4 + fn] != 0)
                                << (fm * 16 + rg * 4 + fn);
            }
        } else if (kt > 8 && !isdiag) {
#pragma unroll
            for (int j = 0; j < 2; ++j) {
                int idx = (kt - 9) * 2 + j;
                int fm = idx >> 2, rg = idx & 3;
#pragma unroll
                for (int fn = 0; fn < 4; ++fn)
                    col_bits |= (unsigned long long)(vb[j * 4 + fn] != 0)
                                << (fn * 16 + fm * 4 + rg);
            }
        }

#pragma unroll
        for (int kk = 0; kk < 2; ++kk) {
            bf16x8 a[4], b[4];
#pragma unroll
            for (int f = 0; f < 4; ++f) {
                a[f] = *reinterpret_cast<const bf16x8*>(Abuf + (wm * 64 + f * 16 + l15) * 64 + kk * 32 + lg * 8);
                b[f] = *reinterpret_cast<const bf16x8*>(Bbuf + (wn * 64 + f * 16 + l15) * 64 + kk * 32 + lg * 8);
            }
#pragma unroll
            for (int fm = 0; fm < 4; ++fm)
#pragma unroll
                for (int fn = 0; fn < 4; ++fn)
                    acc[fm][fn] = __builtin_amdgcn_mfma_f32_16x16x32_bf16(a[fm], b[fn], acc[fm][fn], 0, 0, 0);
        }

        // issue this kt's mask batch (drained by next iteration's barrier)
        if (kt < 8) {
#pragma unroll
            for (int j = 0; j < 2; ++j) {
                int idx = kt * 2 + j;
                int fm = idx >> 2, rg = idx & 3;
                int gr = arow0 + wm * 64 + fm * 16 + lg * 4 + rg;
                size_t base = (size_t)gr * B_N + brow0 + wn * 64 + l15;
                if (is_u8) {
#pragma unroll
                    for (int fn = 0; fn < 4; ++fn) vb[j * 4 + fn] = (int)m8[base + fn * 16];
                } else {
#pragma unroll
                    for (int fn = 0; fn < 4; ++fn) vb[j * 4 + fn] = m32[base + fn * 16];
                }
            }
        } else if (!isdiag) {
#pragma unroll
            for (int j = 0; j < 2; ++j) {
                int idx = (kt - 8) * 2 + j;
                int fm = idx >> 2, rg = idx & 3;
                int ga = arow0 + wm * 64 + fm * 16 + lg * 4 + rg;
                if (is_u8) {
#pragma unroll
                    for (int fn = 0; fn < 4; ++fn)
                        vb[j * 4 + fn] = (int)m8[(size_t)(brow0 + wn * 64 + fn * 16 + l15) * B_N + ga];
                } else {
#pragma unroll
                    for (int fn = 0; fn < 4; ++fn)
                        vb[j * 4 + fn] = m32[(size_t)(brow0 + wn * 64 + fn * 16 + l15) * B_N + ga];
                }
            }
        }
    }

    // pack the last col-side batch (kt=15); compiler inserts the vmcnt wait
    if (!isdiag) {
#pragma unroll
        for (int j = 0; j < 2; ++j) {
            int idx = 14 + j;
            int fm = idx >> 2, rg = idx & 3;
#pragma unroll
            for (int fn = 0; fn < 4; ++fn)
                col_bits |= (unsigned long long)(vb[j * 4 + fn] != 0)
                            << (fn * 16 + fm * 4 + rg);
        }
    }

    // ---- Epilogue ----
    // C/D layout: col = l15, row = lg*4 + reg (within 16x16 frag).
    // E and P reduce per-row (shfl trees + spread atomics); mask*sim goes to
    // a per-block partial (plain store; single-address atomics cost +46us in R3).
    float colE[4] = {0.f, 0.f, 0.f, 0.f};
    float colP[4] = {0.f, 0.f, 0.f, 0.f};
    float Mloc = 0.f;
#pragma unroll
    for (int fm = 0; fm < 4; ++fm) {
#pragma unroll
        for (int rg = 0; rg < 4; ++rg) {
            int gr = arow0 + wm * 64 + fm * 16 + lg * 4 + rg;
            float E = 0.f, Pc = 0.f;
#pragma unroll
            for (int fn = 0; fn < 4; ++fn) {
                int gc = brow0 + wn * 64 + fn * 16 + l15;
                float sim = acc[fm][fn][rg] * 10.0f;
                float e = __expf(sim - 10.0f);
                if (isdiag && gr == gc) e = 0.f;
                E += e;
                if ((row_bits >> (fm * 16 + rg * 4 + fn)) & 1ull) { Mloc += sim; Pc += 1.f; }
                if (!isdiag) {
                    colE[fn] += e;
                    if ((col_bits >> (fn * 16 + fm * 4 + rg)) & 1ull) { Mloc += sim; colP[fn] += 1.f; }
                }
            }
            E += __shfl_xor(E, 1, 64);  Pc += __shfl_xor(Pc, 1, 64);
            E += __shfl_xor(E, 2, 64);  Pc += __shfl_xor(Pc, 2, 64);
            E += __shfl_xor(E, 4, 64);  Pc += __shfl_xor(Pc, 4, 64);
            E += __shfl_xor(E, 8, 64);  Pc += __shfl_xor(Pc, 8, 64);
            if (l15 == 0) {
                atomicAdd(&S[gr], E);
                if (Pc != 0.f) atomicAdd(&Pp[gr], Pc);
            }
        }
    }

    if (!isdiag) {
#pragma unroll
        for (int fn = 0; fn < 4; ++fn) {
            float E = colE[fn], Pc = colP[fn];
            E += __shfl_xor(E, 16, 64);  Pc += __shfl_xor(Pc, 16, 64);
            E += __shfl_xor(E, 32, 64);  Pc += __shfl_xor(Pc, 32, 64);
            if (lg == 0) {
                int gc = brow0 + wn * 64 + fn * 16 + l15;
                atomicAdd(&S[gc], E);
                if (Pc != 0.f) atomicAdd(&Pp[gc], Pc);
            }
        }
    }

    for (int s = 1; s < 64; s <<= 1) Mloc += __shfl_xor(Mloc, s, 64);
    __syncthreads();
    if (lane == 0) Mred[w] = Mloc;
    __syncthreads();
    if (t == 0) Mpart[b0] = Mred[0] + Mred[1] + Mred[2] + Mred[3];
}

__global__ void finalize_kernel(const float* __restrict__ S, const float* __restrict__ P,
                                const float* __restrict__ Mpart, float* __restrict__ out) {
    int t = threadIdx.x;  // 1024
    double a = 0.0;
    for (int i = t; i < B_N; i += 1024) {
        float lse = 10.0f + logf(S[i]);
        a += (double)P[i] * (double)lse;
    }
    for (int i = t; i < NTILES; i += 1024) a -= (double)Mpart[i];
    for (int s = 1; s < 64; s <<= 1) a += __shfl_xor(a, s, 64);
    __shared__ double sh[16];
    if ((t & 63) == 0) sh[t >> 6] = a;
    __syncthreads();
    if (t == 0) {
        double tot = 0.0;
        for (int i = 0; i < 16; ++i) tot += sh[i];
        out[0] = (float)(tot / (double)B_N);
    }
}

extern "C" void kernel_launch(void* const* d_in, const int* in_sizes, int n_in,
                              void* d_out, int out_size, void* d_ws, size_t ws_size,
                              hipStream_t stream) {
    const float* emb = (const float*)d_in[0];
    const void* mask = d_in[1];
    char* ws = (char*)d_ws;
    bf16* xn = (bf16*)ws;
    const size_t XN_BYTES = (size_t)B_N * D_DIM * 2;  // 16MB
    char* red = ws + XN_BYTES;
    float* S = (float*)red;
    float* Pp = (float*)(red + 32768);
    unsigned* flag = (unsigned*)(red + 65536 + 4);
    float* Mpart = (float*)(red + 65536 + 256);

    hipMemsetAsync(red, 0, 65536 + 16, stream);
    detect_mask_kernel<<<64, 256, 0, stream>>>((const unsigned*)mask, flag);
    normalize_kernel<<<B_N, 256, 0, stream>>>(emb, xn);
    sim_kernel<<<NTILES, 256, 0, stream>>>(xn, (const unsigned char*)mask, (const int*)mask,
                                           flag, S, Pp, Mpart);
    finalize_kernel<<<1, 1024, 0, stream>>>(S, Pp, Mpart, (float*)d_out);
}

// Round 7
// 192.754 us; speedup vs baseline: 1.4053x; 1.2848x over previous
//
#include <hip/hip_runtime.h>
#include <hip/hip_bf16.h>
#include <math.h>

#define B_N 8192
#define D_DIM 1024
#define NWORDS 128   // u64 words per mask row
#define NTILES 2080  // 64 diag + 2016 upper-triangle off-diag

using bf16 = __hip_bfloat16;
typedef float f32x4 __attribute__((ext_vector_type(4)));
typedef __bf16 bf16x8 __attribute__((ext_vector_type(8)));

// ws layout:
//   [0, 16MB)                : Xn bf16 [8192][1024]
//   [16MB, 24MB)             : maskbits u64 [8192][128]
//   red = 24MB:
//     red + 0      .. 32KB   : S[8192]  f32  (sum exp(sim-10), j != i)  [atomic, zeroed]
//     red + 32KB   .. 64KB   : P[8192]  f32  (popcount of mask row)     [written by pack]
//     red + 64KB   + 4       : flag u32  (mask-dtype detection)         [atomic, zeroed]
//     red + 64KB+256 ..      : Mpart[2080] f32 (per-block sum mask*sim) [written by sim]

__global__ void detect_mask_kernel(const unsigned* __restrict__ m, unsigned* __restrict__ flag) {
    unsigned c = 0;
    for (int i = blockIdx.x * blockDim.x + threadIdx.x; i < 262144;
         i += gridDim.x * blockDim.x) {
        c += (m[i] > 1u) ? 1u : 0u;
    }
    for (int s = 1; s < 64; s <<= 1) c += __shfl_xor(c, s, 64);
    if ((threadIdx.x & 63) == 0 && c) atomicAdd(flag, c);
}

// One thread per 64-bit output word (64 mask elements). Grid 4096 x 256.
__global__ void pack_mask_kernel(const unsigned char* __restrict__ m8,
                                 const int* __restrict__ m32,
                                 const unsigned* __restrict__ flag,
                                 unsigned long long* __restrict__ bits,
                                 float* __restrict__ P) {
    const bool is_u8 = (*flag != 0u);
    int tid = threadIdx.x;
    size_t w = (size_t)blockIdx.x * 256 + tid;
    unsigned long long word = 0;
    if (is_u8) {
        const uint4* src = (const uint4*)(m8 + w * 64);
#pragma unroll
        for (int q = 0; q < 4; ++q) {
            uint4 v = src[q];
            unsigned cs[4] = {v.x, v.y, v.z, v.w};
#pragma unroll
            for (int c = 0; c < 4; ++c) {
                unsigned u = ((cs[c] & 0x7F7F7F7Fu) + 0x7F7F7F7Fu) | cs[c];
                u &= 0x80808080u;
                unsigned nib = ((u >> 7) & 1u) | ((u >> 14) & 2u) | ((u >> 21) & 4u) | ((u >> 28) & 8u);
                word |= (unsigned long long)nib << ((q * 4 + c) * 4);
            }
        }
    } else {
        const uint4* src = (const uint4*)(m32 + w * 64);
#pragma unroll
        for (int q = 0; q < 16; ++q) {
            uint4 v = src[q];
            unsigned nib = (unsigned)(v.x != 0) | ((unsigned)(v.y != 0) << 1) |
                           ((unsigned)(v.z != 0) << 2) | ((unsigned)(v.w != 0) << 3);
            word |= (unsigned long long)nib << (q * 4);
        }
    }
    bits[w] = word;
    float pc = (float)__popcll(word);
    for (int s = 1; s < 64; s <<= 1) pc += __shfl_xor(pc, s, 64);
    __shared__ float wsum[4];
    if ((tid & 63) == 0) wsum[tid >> 6] = pc;
    __syncthreads();
    if (tid == 0)   P[blockIdx.x * 2]     = wsum[0] + wsum[1];
    if (tid == 128) P[blockIdx.x * 2 + 1] = wsum[2] + wsum[3];
}

__global__ void normalize_kernel(const float* __restrict__ emb, bf16* __restrict__ xn) {
    int row = blockIdx.x;
    int t = threadIdx.x;  // 256 threads, 4 floats each
    const float4* src = (const float4*)(emb + (size_t)row * D_DIM);
    float4 v = src[t];
    float ss = v.x * v.x + v.y * v.y + v.z * v.z + v.w * v.w;
    for (int s = 1; s < 64; s <<= 1) ss += __shfl_xor(ss, s, 64);
    __shared__ float wss[4];
    if ((t & 63) == 0) wss[t >> 6] = ss;
    __syncthreads();
    float tot = wss[0] + wss[1] + wss[2] + wss[3];
    float scale = 1.0f / fmaxf(sqrtf(tot), 1e-12f);
    ushort4 o;
    o.x = __builtin_bit_cast(unsigned short, __float2bfloat16(v.x * scale));
    o.y = __builtin_bit_cast(unsigned short, __float2bfloat16(v.y * scale));
    o.z = __builtin_bit_cast(unsigned short, __float2bfloat16(v.z * scale));
    o.w = __builtin_bit_cast(unsigned short, __float2bfloat16(v.w * scale));
    *reinterpret_cast<ushort4*>(xn + (size_t)row * D_DIM + t * 4) = o;
}

// Upper-triangle tiling: 64 diag + 2016 off-diag = 2080 blocks.
// 128x128 tile, BK=64, 4 waves (2x2), each wave 64x64 = 4x4 frags of 16x16x32.
// R4's proven single-buffer 2-barrier K-loop, PLUS T2 LDS XOR-swizzle:
// LDS slot (row, chunk) holds global chunk = chunk ^ (row&7); achieved by
// pre-swizzling the per-lane GLOBAL source (global_load_lds dest must stay
// linear, rule 21) and XOR-ing the ds_read chunk the same way. Kills the
// 16-way bank conflict (16 lanes reading rows at 128B stride, same chunk col).
__global__ __launch_bounds__(256, 2) void sim_kernel(
    const bf16* __restrict__ xn,
    const unsigned long long* __restrict__ mbits,
    float* __restrict__ S, float* __restrict__ Mpart)
{
    __shared__ bf16 Abuf[128 * 64];
    __shared__ bf16 Bbuf[128 * 64];
    __shared__ float Mred[4];

    // XCD-aware bijective swizzle (2080 % 8 == 0 -> 260 per XCD)
    int b0 = blockIdx.x;
    int tile = (b0 & 7) * 260 + (b0 >> 3);
    int by, bx;
    bool isdiag;
    if (tile < 64) {
        by = bx = tile;
        isdiag = true;
    } else {
        int j = tile - 64;  // [0, 2016)
        int p = (int)((sqrt((double)(8 * j + 1)) + 1.0) * 0.5);
        while (p * (p - 1) / 2 > j) --p;
        while ((p + 1) * p / 2 <= j) ++p;
        int q = j - p * (p - 1) / 2;
        by = q; bx = p;  // by < bx
        isdiag = false;
    }

    int t = threadIdx.x;
    int w = t >> 6, lane = t & 63;
    int wm = w >> 1, wn = w & 1;
    int l15 = lane & 15, lg = lane >> 4;

    f32x4 acc[4][4];
#pragma unroll
    for (int i = 0; i < 4; i++)
#pragma unroll
        for (int j = 0; j < 4; j++) acc[i][j] = {0.f, 0.f, 0.f, 0.f};

    int arow0 = by << 7;
    int brow0 = bx << 7;

    // Staging geometry: element-of-16B index e = i*256 + w*64 + lane covers
    // tile row r = e>>3 (r&7 == lane>>3) and dest chunk c = e&7 (== lane&7).
    // Swizzled source chunk: c_src = (lane&7) ^ (lane>>3); element offset:
    int ebase0 = w * 64;
    int c80 = ((lane & 7) ^ (lane >> 3)) << 3;
    int rlane = (w << 3) + (lane >> 3);  // w*8 + lane>>3; full r = i*32 + rlane
    int xr = l15 & 7;                    // read-side XOR (row&7 for frag rows)

    for (int kt = 0; kt < D_DIM; kt += 64) {
#pragma unroll
        for (int i = 0; i < 4; ++i) {
            int ebase = i * 256 + ebase0;    // wave-uniform LDS base (linear dest)
            int r = i * 32 + rlane;
            const bf16* gA = xn + (size_t)(arow0 + r) * D_DIM + kt + c80;
            const bf16* gB = xn + (size_t)(brow0 + r) * D_DIM + kt + c80;
            char* lA = (char*)Abuf + (size_t)ebase * 16;
            char* lB = (char*)Bbuf + (size_t)ebase * 16;
            __builtin_amdgcn_global_load_lds((const __attribute__((address_space(1))) void*)gA,
                                             (__attribute__((address_space(3))) void*)lA, 16, 0, 0);
            __builtin_amdgcn_global_load_lds((const __attribute__((address_space(1))) void*)gB,
                                             (__attribute__((address_space(3))) void*)lB, 16, 0, 0);
        }
        __syncthreads();
#pragma unroll
        for (int kk = 0; kk < 2; ++kk) {
            bf16x8 a[4], b[4];
#pragma unroll
            for (int f = 0; f < 4; ++f) {
                int ca = (((kk << 2) | lg) ^ xr) << 3;  // swizzled chunk, elements
                a[f] = *reinterpret_cast<const bf16x8*>(Abuf + (wm * 64 + f * 16 + l15) * 64 + ca);
                b[f] = *reinterpret_cast<const bf16x8*>(Bbuf + (wn * 64 + f * 16 + l15) * 64 + ca);
            }
#pragma unroll
            for (int fm = 0; fm < 4; ++fm)
#pragma unroll
                for (int fn = 0; fn < 4; ++fn)
                    acc[fm][fn] = __builtin_amdgcn_mfma_f32_16x16x32_bf16(a[fm], b[fn], acc[fm][fn], 0, 0, 0);
        }
        __syncthreads();
    }

    // ---- Epilogue ----
    // C/D layout: col = l15, row = lg*4 + reg (within 16x16 frag).
    float colE[4] = {0.f, 0.f, 0.f, 0.f};
    unsigned long long wcol[4] = {0, 0, 0, 0};
    if (!isdiag) {
#pragma unroll
        for (int fn = 0; fn < 4; ++fn) {
            int gc = brow0 + wn * 64 + fn * 16 + l15;
            wcol[fn] = mbits[(size_t)gc * NWORDS + by * 2 + wm];
        }
    }

    float Mloc = 0.f;
#pragma unroll
    for (int fm = 0; fm < 4; ++fm) {
#pragma unroll
        for (int reg = 0; reg < 4; ++reg) {
            int lr = fm * 16 + lg * 4 + reg;          // row within wave tile
            int gr = arow0 + wm * 64 + lr;
            unsigned long long wrow = mbits[(size_t)gr * NWORDS + bx * 2 + wn];
            float E = 0.f;
#pragma unroll
            for (int fn = 0; fn < 4; ++fn) {
                int gc = brow0 + wn * 64 + fn * 16 + l15;
                float sim = acc[fm][fn][reg] * 10.0f;
                float e = __expf(sim - 10.0f);
                if (isdiag && gr == gc) e = 0.f;
                E += e;
                if ((wrow >> (fn * 16 + l15)) & 1ull) Mloc += sim;
                if (!isdiag) {
                    colE[fn] += e;
                    if ((wcol[fn] >> lr) & 1ull) Mloc += sim;
                }
            }
            E += __shfl_xor(E, 1, 64);
            E += __shfl_xor(E, 2, 64);
            E += __shfl_xor(E, 4, 64);
            E += __shfl_xor(E, 8, 64);
            if (l15 == 0) atomicAdd(&S[gr], E);
        }
    }

    if (!isdiag) {
#pragma unroll
        for (int fn = 0; fn < 4; ++fn) {
            float E = colE[fn];
            E += __shfl_xor(E, 16, 64);
            E += __shfl_xor(E, 32, 64);
            if (lg == 0) atomicAdd(&S[brow0 + wn * 64 + fn * 16 + l15], E);
        }
    }

    for (int s = 1; s < 64; s <<= 1) Mloc += __shfl_xor(Mloc, s, 64);
    if (lane == 0) Mred[w] = Mloc;
    __syncthreads();
    if (t == 0) Mpart[b0] = Mred[0] + Mred[1] + Mred[2] + Mred[3];
}

__global__ void finalize_kernel(const float* __restrict__ S, const float* __restrict__ P,
                                const float* __restrict__ Mpart, float* __restrict__ out) {
    int t = threadIdx.x;  // 1024
    double a = 0.0;
    for (int i = t; i < B_N; i += 1024) {
        float lse = 10.0f + logf(S[i]);
        a += (double)P[i] * (double)lse;
    }
    for (int i = t; i < NTILES; i += 1024) a -= (double)Mpart[i];
    for (int s = 1; s < 64; s <<= 1) a += __shfl_xor(a, s, 64);
    __shared__ double sh[16];
    if ((t & 63) == 0) sh[t >> 6] = a;
    __syncthreads();
    if (t == 0) {
        double tot = 0.0;
        for (int i = 0; i < 16; ++i) tot += sh[i];
        out[0] = (float)(tot / (double)B_N);
    }
}

extern "C" void kernel_launch(void* const* d_in, const int* in_sizes, int n_in,
                              void* d_out, int out_size, void* d_ws, size_t ws_size,
                              hipStream_t stream) {
    const float* emb = (const float*)d_in[0];
    const void* mask = d_in[1];
    char* ws = (char*)d_ws;
    bf16* xn = (bf16*)ws;
    const size_t XN_BYTES = (size_t)B_N * D_DIM * 2;              // 16MB
    unsigned long long* mbits = (unsigned long long*)(ws + XN_BYTES);
    const size_t MB_BYTES = (size_t)B_N * NWORDS * 8;             // 8MB
    char* red = ws + XN_BYTES + MB_BYTES;
    float* S = (float*)red;
    float* P = (float*)(red + 32768);
    unsigned* flag = (unsigned*)(red + 65536 + 4);
    float* Mpart = (float*)(red + 65536 + 256);

    hipMemsetAsync(red, 0, 65536 + 16, stream);
    detect_mask_kernel<<<64, 256, 0, stream>>>((const unsigned*)mask, flag);
    pack_mask_kernel<<<4096, 256, 0, stream>>>((const unsigned char*)mask, (const int*)mask,
                                               flag, mbits, P);
    normalize_kernel<<<B_N, 256, 0, stream>>>(emb, xn);
    sim_kernel<<<NTILES, 256, 0, stream>>>(xn, mbits, S, Mpart);
    finalize_kernel<<<1, 1024, 0, stream>>>(S, P, Mpart, (float*)d_out);
}